// Round 5
// baseline (1333.131 us; speedup 1.0000x reference)
//
#include <hip/hip_runtime.h>
#include <hip/hip_bf16.h>

#define NNODES 320000
#define NEDGES 960000
#define NPART 8
#define PARTSZ (NNODES / NPART)  // 40000

typedef __attribute__((ext_vector_type(8))) short short8;
typedef __attribute__((ext_vector_type(4))) float f32x4;

__device__ __forceinline__ float b2f(unsigned short u) {
    return __uint_as_float(((unsigned)u) << 16);
}
__device__ __forceinline__ unsigned short f2b(float f) {
    __hip_bfloat16 h = __float2bfloat16(f);
    union { __hip_bfloat16 h; unsigned short u; } cv;
    cv.h = h;
    return cv.u;
}

// ---------------- CSR build (XCD-partitioned: blockIdx&7 == node-range owner) ----------------

__global__ void k_zero(int* p, int n) {
    int i = blockIdx.x * blockDim.x + threadIdx.x;
    int s = gridDim.x * blockDim.x;
    for (; i < n; i += s) p[i] = 0;
}

__global__ void k_count(const int* __restrict__ edges, int* __restrict__ deg) {
    int r = blockIdx.x & (NPART - 1);
    int lo = r * PARTSZ, hi = lo + PARTSZ;
    int i = (blockIdx.x >> 3) * blockDim.x + threadIdx.x;
    int s = (gridDim.x >> 3) * blockDim.x;
    for (; i < NEDGES; i += s) {
        int2 e = *(const int2*)&edges[2 * i];
        if (e.x >= lo && e.x < hi) atomicAdd(&deg[e.x], 1);
        if (e.y >= lo && e.y < hi) atomicAdd(&deg[e.y], 1);
    }
}

#define SCAN_BLOCK 256
#define SCAN_ITEMS 8
#define SCAN_CHUNK 2048
#define SCAN_NB 157  // ceil(320000/2048)

__global__ void k_scan1(const int* __restrict__ deg, int* __restrict__ bsum) {
    __shared__ int sd[SCAN_BLOCK];
    int b = blockIdx.x, t = threadIdx.x;
    int base = b * SCAN_CHUNK + t * SCAN_ITEMS;
    int s = 0;
    for (int i = 0; i < SCAN_ITEMS; i++) {
        int g = base + i;
        if (g < NNODES) s += deg[g];
    }
    sd[t] = s;
    __syncthreads();
    for (int off = 128; off > 0; off >>= 1) {
        if (t < off) sd[t] += sd[t + off];
        __syncthreads();
    }
    if (t == 0) bsum[b] = sd[0];
}

// parallel exclusive scan of the 157 block sums (replaces serial 1-thread loop)
__global__ void k_scan2(int* bsum, int* rowptr) {
    __shared__ int sd[256];
    int t = threadIdx.x;
    int v = (t < SCAN_NB) ? bsum[t] : 0;
    sd[t] = v;
    __syncthreads();
    for (int off = 1; off < 256; off <<= 1) {
        int x = (t >= off) ? sd[t - off] : 0;
        __syncthreads();
        sd[t] += x;
        __syncthreads();
    }
    if (t < SCAN_NB) bsum[t] = sd[t] - v;  // exclusive prefix
    if (t == SCAN_NB - 1) rowptr[NNODES] = sd[t];
}

__global__ void k_scan3(int* __restrict__ deg_cursor, int* __restrict__ rowptr,
                        const int* __restrict__ bsum, float* __restrict__ degf) {
    __shared__ int sd[SCAN_BLOCK];
    int b = blockIdx.x, t = threadIdx.x;
    int base = b * SCAN_CHUNK + t * SCAN_ITEMS;
    int v[SCAN_ITEMS];
    int s = 0;
    for (int i = 0; i < SCAN_ITEMS; i++) {
        int g = base + i;
        v[i] = (g < NNODES) ? deg_cursor[g] : 0;
        s += v[i];
    }
    sd[t] = s;
    __syncthreads();
    for (int off = 1; off < SCAN_BLOCK; off <<= 1) {
        int x = (t >= off) ? sd[t - off] : 0;
        __syncthreads();
        sd[t] += x;
        __syncthreads();
    }
    int prefix = bsum[b] + (sd[t] - s);  // exclusive over threads
    for (int i = 0; i < SCAN_ITEMS; i++) {
        int g = base + i;
        if (g < NNODES) {
            rowptr[g] = prefix;
            deg_cursor[g] = prefix;  // cursor init
            degf[g] = (float)v[i];
            prefix += v[i];
        }
    }
}

__global__ void k_fill(const int* __restrict__ edges, int* __restrict__ cursor,
                       int* __restrict__ adj) {
    int r = blockIdx.x & (NPART - 1);
    int lo = r * PARTSZ, hi = lo + PARTSZ;
    int i = (blockIdx.x >> 3) * blockDim.x + threadIdx.x;
    int s = (gridDim.x >> 3) * blockDim.x;
    for (; i < NEDGES; i += s) {
        int2 e = *(const int2*)&edges[2 * i];
        if (e.x >= lo && e.x < hi) adj[atomicAdd(&cursor[e.x], 1)] = e.y;
        if (e.y >= lo && e.y < hi) adj[atomicAdd(&cursor[e.y], 1)] = e.x;
    }
}

// ---------------- conversions ----------------

__global__ void k_cvt(const float* __restrict__ f, unsigned short* __restrict__ o,
                      long n4) {
    long i = (long)blockIdx.x * blockDim.x + threadIdx.x;
    long s = (long)gridDim.x * blockDim.x;
    for (; i < n4; i += s) {
        float4 v = *(const float4*)&f[i * 4];
        uint2 u;
        u.x = (unsigned)f2b(v.x) | ((unsigned)f2b(v.y) << 16);
        u.y = (unsigned)f2b(v.z) | ((unsigned)f2b(v.w) << 16);
        *(uint2*)&o[i * 4] = u;
    }
}

// Wt[c][k], k in [0,256): k<128 -> W0[k][c], else W1[k-128][c]
__global__ void k_cvtW(const float* __restrict__ W0, const float* __restrict__ W1,
                       unsigned short* __restrict__ Wt) {
    int idx = blockIdx.x * blockDim.x + threadIdx.x;
    if (idx >= 128 * 256) return;
    int c = idx >> 8, k = idx & 255;
    float v = (k < 128) ? W0[k * 128 + c] : W1[(k - 128) * 128 + c];
    Wt[idx] = f2b(v);
}

// ---------------- fused layer: gather + dual GEMM + epilogue ----------------
// out = relu(x*W0 + (sum_nbr x_j)*W1 + b0 + deg*b1) [+feat]
// 64-row tile, 512 thr = 8 waves. Phase A: stage X tile. Phase B: wave w
// gathers neighbor-row sums for nodes w*8..w*8+7 straight into Ss (f32 regs,
// bf16 to LDS). Phase C: 2Mx4N wave-tiled MFMA (32x32/wave), K=256.
// Grid-stride over 5000 tiles; xin/out are distinct buffers (ping-pong).

#define XLD 136  // padded LDS row stride (bf16): 272 B

template <int RES, int L>
__global__ __launch_bounds__(512, 4) void k_layer(
    const unsigned short* __restrict__ xin, const int* __restrict__ rowptr,
    const int* __restrict__ adj, const unsigned short* __restrict__ Wt,
    const float* __restrict__ b0, const float* __restrict__ b1,
    const float* __restrict__ degf, const unsigned short* __restrict__ feat,
    unsigned short* __restrict__ out) {
    __shared__ __align__(16) unsigned short Xs[64 * XLD];
    __shared__ __align__(16) unsigned short Ss[64 * XLD];

    int tid = threadIdx.x;
    int wave = tid >> 6, lane = tid & 63;
    int wm = wave >> 2, wn = wave & 3;
    int kg = (lane >> 4) << 3;  // 0,8,16,24
    int cl = lane & 15;
    int slot = lane >> 4;        // gather neighbor sub-slot 0..3
    int cb = cl * 8;             // bf16 column base (16 B chunk)

    for (int tile = blockIdx.x; tile < NNODES / 64; tile += gridDim.x) {
        int rowBase = tile * 64;
        __syncthreads();  // previous tile's LDS reads complete

        // Phase A: stage X tile (coalesced)
#pragma unroll
        for (int it = 0; it < 2; ++it) {
            int e = (it * 512 + tid) * 8;
            int r = e >> 7, k = e & 127;
            *(uint4*)&Xs[r * XLD + k] =
                *(const uint4*)&xin[(size_t)(rowBase + r) * 128 + k];
        }

        // Phase B: gather neighbor sums into Ss (wave handles 8 nodes)
        for (int nl = 0; nl < 8; ++nl) {
            int nodeLocal = wave * 8 + nl;
            int node = rowBase + nodeLocal;
            int s = rowptr[node], e = rowptr[node + 1];
            float a[8];
#pragma unroll
            for (int q = 0; q < 8; q++) a[q] = 0.f;
            for (int p = s; p < e; p += 8) {
                int i0 = p + slot, i1 = p + slot + 4;
                uint4 v0 = make_uint4(0, 0, 0, 0), v1 = make_uint4(0, 0, 0, 0);
                if (i0 < e) {
                    int j = adj[i0];
                    v0 = *(const uint4*)&xin[(size_t)j * 128 + cb];
                }
                if (i1 < e) {
                    int j = adj[i1];
                    v1 = *(const uint4*)&xin[(size_t)j * 128 + cb];
                }
                unsigned w0[4] = {v0.x, v0.y, v0.z, v0.w};
                unsigned w1[4] = {v1.x, v1.y, v1.z, v1.w};
#pragma unroll
                for (int q = 0; q < 4; q++) {
                    a[2 * q] += b2f(w0[q] & 0xffff) + b2f(w1[q] & 0xffff);
                    a[2 * q + 1] += b2f(w0[q] >> 16) + b2f(w1[q] >> 16);
                }
            }
#pragma unroll
            for (int q = 0; q < 8; q++) a[q] += __shfl_xor(a[q], 16, 64);
#pragma unroll
            for (int q = 0; q < 8; q++) a[q] += __shfl_xor(a[q], 32, 64);
            if (lane < 16) {
                uint4 o;
                o.x = (unsigned)f2b(a[0]) | ((unsigned)f2b(a[1]) << 16);
                o.y = (unsigned)f2b(a[2]) | ((unsigned)f2b(a[3]) << 16);
                o.z = (unsigned)f2b(a[4]) | ((unsigned)f2b(a[5]) << 16);
                o.w = (unsigned)f2b(a[6]) | ((unsigned)f2b(a[7]) << 16);
                *(uint4*)&Ss[nodeLocal * XLD + cb] = o;
            }
        }
        __syncthreads();

        // Phase C: MFMA dual-GEMM
        f32x4 acc[2][2];
#pragma unroll
        for (int i = 0; i < 2; i++)
#pragma unroll
            for (int j = 0; j < 2; j++) acc[i][j] = (f32x4){0.f, 0.f, 0.f, 0.f};

#pragma unroll
        for (int ks = 0; ks < 8; ++ks) {
            const unsigned short* src = (ks < 4) ? Xs : Ss;
            int kk = (ks & 3) * 32 + kg;
            short8 aF[2];
#pragma unroll
            for (int mf = 0; mf < 2; ++mf) {
                int r = wm * 32 + mf * 16 + cl;
                aF[mf] = *(const short8*)&src[r * XLD + kk];
            }
#pragma unroll
            for (int nf = 0; nf < 2; nf++) {
                int c = wn * 32 + nf * 16 + cl;
                short8 bF = *(const short8*)&Wt[(size_t)c * 256 + ks * 32 + kg];
#pragma unroll
                for (int mf = 0; mf < 2; mf++)
                    acc[mf][nf] = __builtin_amdgcn_mfma_f32_16x16x32_bf16(
                        aF[mf], bF, acc[mf][nf], 0, 0, 0);
            }
        }

        // epilogue: D col = lane&15, row = (lane>>4)*4+q (verified layout)
#pragma unroll
        for (int nf = 0; nf < 2; nf++) {
            int c = wn * 32 + nf * 16 + cl;
            float bias0 = b0[c], bias1 = b1[c];
#pragma unroll
            for (int mf = 0; mf < 2; mf++) {
                int r0 = rowBase + wm * 32 + mf * 16 + ((lane >> 4) << 2);
                f32x4 d = acc[mf][nf];
#pragma unroll
                for (int q = 0; q < 4; q++) {
                    int r = r0 + q;
                    float v = d[q] + bias0 + degf[r] * bias1;
                    v = fmaxf(v, 0.f);
                    if (RES) v += b2f(feat[(size_t)r * 128 + c]);
                    out[(size_t)r * 128 + c] = f2b(v);
                }
            }
        }
    }
}

// ---------------- fused final layer: gather + 256->3 dot, straight to d_out ----------------
// 64 nodes/tile, 256 thr = 4 waves. Wave gathers 16 nodes; then 4 thr/node dot.

__global__ __launch_bounds__(256) void k_finF(
    const unsigned short* __restrict__ act, const int* __restrict__ rowptr,
    const int* __restrict__ adj, const float* __restrict__ W0,
    const float* __restrict__ W1, const float* __restrict__ b0,
    const float* __restrict__ b1, const float* __restrict__ degf,
    float* __restrict__ out) {
    __shared__ __align__(16) unsigned short xa[64 * XLD];
    __shared__ __align__(16) unsigned short xs2[64 * XLD];
    __shared__ float Wf[768];
    __shared__ float ps[64][4][4];

    int tid = threadIdx.x;
    int wave = tid >> 6, lane = tid & 63;
    int slot = lane >> 4;
    int cb = (lane & 15) * 8;

    for (int idx = tid; idx < 384; idx += 256) {
        Wf[idx] = W0[idx];
        Wf[384 + idx] = W1[idx];
    }

    for (int tile = blockIdx.x; tile < NNODES / 64; tile += gridDim.x) {
        int nodeBase = tile * 64;
        __syncthreads();  // previous tile reads done (also covers Wf store)

#pragma unroll
        for (int it = 0; it < 4; ++it) {
            int e = (it * 256 + tid) * 8;
            int r = e >> 7, k = e & 127;
            *(uint4*)&xa[r * XLD + k] =
                *(const uint4*)&act[(size_t)(nodeBase + r) * 128 + k];
        }

        for (int nl = 0; nl < 16; ++nl) {
            int nodeLocal = wave * 16 + nl;
            int node = nodeBase + nodeLocal;
            int s = rowptr[node], e = rowptr[node + 1];
            float a[8];
#pragma unroll
            for (int q = 0; q < 8; q++) a[q] = 0.f;
            for (int p = s; p < e; p += 8) {
                int i0 = p + slot, i1 = p + slot + 4;
                uint4 v0 = make_uint4(0, 0, 0, 0), v1 = make_uint4(0, 0, 0, 0);
                if (i0 < e) {
                    int j = adj[i0];
                    v0 = *(const uint4*)&act[(size_t)j * 128 + cb];
                }
                if (i1 < e) {
                    int j = adj[i1];
                    v1 = *(const uint4*)&act[(size_t)j * 128 + cb];
                }
                unsigned w0[4] = {v0.x, v0.y, v0.z, v0.w};
                unsigned w1[4] = {v1.x, v1.y, v1.z, v1.w};
#pragma unroll
                for (int q = 0; q < 4; q++) {
                    a[2 * q] += b2f(w0[q] & 0xffff) + b2f(w1[q] & 0xffff);
                    a[2 * q + 1] += b2f(w0[q] >> 16) + b2f(w1[q] >> 16);
                }
            }
#pragma unroll
            for (int q = 0; q < 8; q++) a[q] += __shfl_xor(a[q], 16, 64);
#pragma unroll
            for (int q = 0; q < 8; q++) a[q] += __shfl_xor(a[q], 32, 64);
            if (lane < 16) {
                uint4 o;
                o.x = (unsigned)f2b(a[0]) | ((unsigned)f2b(a[1]) << 16);
                o.y = (unsigned)f2b(a[2]) | ((unsigned)f2b(a[3]) << 16);
                o.z = (unsigned)f2b(a[4]) | ((unsigned)f2b(a[5]) << 16);
                o.w = (unsigned)f2b(a[6]) | ((unsigned)f2b(a[7]) << 16);
                *(uint4*)&xs2[nodeLocal * XLD + cb] = o;
            }
        }
        __syncthreads();

        int n = tid >> 2, q = tid & 3;
        const unsigned short* src = (q < 2) ? xa : xs2;
        int kloc = (q & 1) * 64;
        float a0 = 0.f, a1 = 0.f, a2 = 0.f;
#pragma unroll
        for (int kk = 0; kk < 64; kk += 8) {
            uint4 v = *(const uint4*)&src[n * XLD + kloc + kk];
            unsigned vv[4] = {v.x, v.y, v.z, v.w};
#pragma unroll
            for (int t = 0; t < 4; t++) {
                int kgl = q * 64 + kk + 2 * t;
                float x0 = b2f(vv[t] & 0xffff), x1 = b2f(vv[t] >> 16);
                const float* w = &Wf[kgl * 3];
                a0 += x0 * w[0] + x1 * w[3];
                a1 += x0 * w[1] + x1 * w[4];
                a2 += x0 * w[2] + x1 * w[5];
            }
        }
        ps[n][q][0] = a0;
        ps[n][q][1] = a1;
        ps[n][q][2] = a2;
        __syncthreads();
        if (q == 0) {
            int node = nodeBase + n;
            float dg = degf[node];
#pragma unroll
            for (int c = 0; c < 3; c++) {
                float d = ps[n][0][c] + ps[n][1][c] + ps[n][2][c] + ps[n][3][c] +
                          b0[c] + dg * b1[c];
                out[(size_t)node * 3 + c] = d;
            }
        }
    }
}

// ---------------- launch ----------------

extern "C" void kernel_launch(void* const* d_in, const int* in_sizes, int n_in,
                              void* d_out, int out_size, void* d_ws, size_t ws_size,
                              hipStream_t stream) {
    const float* features = (const float*)d_in[0];
    const int* edges = (const int*)d_in[1];
    const float *W0[4], *B0[4], *W1[4], *B1[4];
    for (int i = 0; i < 4; i++) {
        W0[i] = (const float*)d_in[2 + 4 * i];
        B0[i] = (const float*)d_in[3 + 4 * i];
        W1[i] = (const float*)d_in[4 + 4 * i];
        B1[i] = (const float*)d_in[5 + 4 * i];
    }

    char* p = (char*)d_ws;
    auto alloc = [&](size_t bytes) {
        void* r = (void*)p;
        p += (bytes + 255) & ~(size_t)255;
        return r;
    };
    int* rowptr = (int*)alloc((NNODES + 1) * sizeof(int));
    int* cursor = (int*)alloc((NNODES + 1) * sizeof(int));
    float* degf = (float*)alloc(NNODES * sizeof(float));
    int* adj = (int*)alloc((size_t)2 * NEDGES * sizeof(int));
    int* bsum = (int*)alloc(1024);
    unsigned short* feat_bf = (unsigned short*)alloc((size_t)NNODES * 128 * 2);
    unsigned short* actA = (unsigned short*)alloc((size_t)NNODES * 128 * 2);
    unsigned short* actB = (unsigned short*)alloc((size_t)NNODES * 128 * 2);
    unsigned short* Wtb = (unsigned short*)alloc((size_t)3 * 128 * 256 * 2);

    // CSR build (XCD-partitioned count/fill)
    k_zero<<<1024, 256, 0, stream>>>(cursor, NNODES + 1);
    k_count<<<2048, 256, 0, stream>>>(edges, cursor);
    k_scan1<<<SCAN_NB, SCAN_BLOCK, 0, stream>>>(cursor, bsum);
    k_scan2<<<1, 256, 0, stream>>>(bsum, rowptr);
    k_scan3<<<SCAN_NB, SCAN_BLOCK, 0, stream>>>(cursor, rowptr, bsum, degf);
    k_fill<<<2048, 256, 0, stream>>>(edges, cursor, adj);

    // conversions
    k_cvt<<<2048, 256, 0, stream>>>(features, feat_bf, (long)NNODES * 128 / 4);
    for (int l = 0; l < 3; l++)
        k_cvtW<<<128, 256, 0, stream>>>(W0[l], W1[l], Wtb + (size_t)l * 128 * 256);

    // fused layers (ping-pong activations)
    k_layer<0, 0><<<1250, 512, 0, stream>>>(feat_bf, rowptr, adj, Wtb, B0[0], B1[0],
                                            degf, nullptr, actA);
    k_layer<0, 1><<<1250, 512, 0, stream>>>(actA, rowptr, adj, Wtb + 128 * 256,
                                            B0[1], B1[1], degf, nullptr, actB);
    k_layer<1, 2><<<1250, 512, 0, stream>>>(actB, rowptr, adj, Wtb + 2 * 128 * 256,
                                            B0[2], B1[2], degf, feat_bf, actA);
    // fused final layer
    k_finF<<<2500, 256, 0, stream>>>(actA, rowptr, adj, W0[3], W1[3], B0[3], B1[3],
                                     degf, (float*)d_out);
}

// Round 6
// 1168.988 us; speedup vs baseline: 1.1404x; 1.1404x over previous
//
#include <hip/hip_runtime.h>
#include <hip/hip_bf16.h>

#define NNODES 320000
#define NEDGES 960000
#define NPART 8
#define PARTSZ (NNODES / NPART)  // 40000

typedef __attribute__((ext_vector_type(8))) short short8;
typedef __attribute__((ext_vector_type(4))) float f32x4;

__device__ __forceinline__ float b2f(unsigned short u) {
    return __uint_as_float(((unsigned)u) << 16);
}
__device__ __forceinline__ unsigned short f2b(float f) {
    __hip_bfloat16 h = __float2bfloat16(f);
    union { __hip_bfloat16 h; unsigned short u; } cv;
    cv.h = h;
    return cv.u;
}

// ---------------- CSR build (XCD-partitioned: blockIdx&7 == node-range owner) ----------------

__global__ void k_zero(int* p, int n) {
    int i = blockIdx.x * blockDim.x + threadIdx.x;
    int s = gridDim.x * blockDim.x;
    for (; i < n; i += s) p[i] = 0;
}

__global__ void k_count(const int* __restrict__ edges, int* __restrict__ deg) {
    int r = blockIdx.x & (NPART - 1);
    int lo = r * PARTSZ, hi = lo + PARTSZ;
    int i = (blockIdx.x >> 3) * blockDim.x + threadIdx.x;
    int s = (gridDim.x >> 3) * blockDim.x;
    for (; i < NEDGES; i += s) {
        int2 e = *(const int2*)&edges[2 * i];
        if (e.x >= lo && e.x < hi) atomicAdd(&deg[e.x], 1);
        if (e.y >= lo && e.y < hi) atomicAdd(&deg[e.y], 1);
    }
}

#define SCAN_BLOCK 256
#define SCAN_ITEMS 8
#define SCAN_CHUNK 2048
#define SCAN_NB 157  // ceil(320000/2048)

__global__ void k_scan1(const int* __restrict__ deg, int* __restrict__ bsum) {
    __shared__ int sd[SCAN_BLOCK];
    int b = blockIdx.x, t = threadIdx.x;
    int base = b * SCAN_CHUNK + t * SCAN_ITEMS;
    int s = 0;
    for (int i = 0; i < SCAN_ITEMS; i++) {
        int g = base + i;
        if (g < NNODES) s += deg[g];
    }
    sd[t] = s;
    __syncthreads();
    for (int off = 128; off > 0; off >>= 1) {
        if (t < off) sd[t] += sd[t + off];
        __syncthreads();
    }
    if (t == 0) bsum[b] = sd[0];
}

// parallel exclusive scan of the 157 block sums
__global__ void k_scan2(int* bsum, int* rowptr) {
    __shared__ int sd[256];
    int t = threadIdx.x;
    int v = (t < SCAN_NB) ? bsum[t] : 0;
    sd[t] = v;
    __syncthreads();
    for (int off = 1; off < 256; off <<= 1) {
        int x = (t >= off) ? sd[t - off] : 0;
        __syncthreads();
        sd[t] += x;
        __syncthreads();
    }
    if (t < SCAN_NB) bsum[t] = sd[t] - v;  // exclusive prefix
    if (t == SCAN_NB - 1) rowptr[NNODES] = sd[t];
}

__global__ void k_scan3(int* __restrict__ deg_cursor, int* __restrict__ rowptr,
                        const int* __restrict__ bsum, float* __restrict__ degf) {
    __shared__ int sd[SCAN_BLOCK];
    int b = blockIdx.x, t = threadIdx.x;
    int base = b * SCAN_CHUNK + t * SCAN_ITEMS;
    int v[SCAN_ITEMS];
    int s = 0;
    for (int i = 0; i < SCAN_ITEMS; i++) {
        int g = base + i;
        v[i] = (g < NNODES) ? deg_cursor[g] : 0;
        s += v[i];
    }
    sd[t] = s;
    __syncthreads();
    for (int off = 1; off < SCAN_BLOCK; off <<= 1) {
        int x = (t >= off) ? sd[t - off] : 0;
        __syncthreads();
        sd[t] += x;
        __syncthreads();
    }
    int prefix = bsum[b] + (sd[t] - s);  // exclusive over threads
    for (int i = 0; i < SCAN_ITEMS; i++) {
        int g = base + i;
        if (g < NNODES) {
            rowptr[g] = prefix;
            deg_cursor[g] = prefix;  // cursor init
            degf[g] = (float)v[i];
            prefix += v[i];
        }
    }
}

__global__ void k_fill(const int* __restrict__ edges, int* __restrict__ cursor,
                       int* __restrict__ adj) {
    int r = blockIdx.x & (NPART - 1);
    int lo = r * PARTSZ, hi = lo + PARTSZ;
    int i = (blockIdx.x >> 3) * blockDim.x + threadIdx.x;
    int s = (gridDim.x >> 3) * blockDim.x;
    for (; i < NEDGES; i += s) {
        int2 e = *(const int2*)&edges[2 * i];
        if (e.x >= lo && e.x < hi) adj[atomicAdd(&cursor[e.x], 1)] = e.y;
        if (e.y >= lo && e.y < hi) adj[atomicAdd(&cursor[e.y], 1)] = e.x;
    }
}

// ---------------- conversions ----------------

__global__ void k_cvt(const float* __restrict__ f, unsigned short* __restrict__ o,
                      long n4) {
    long i = (long)blockIdx.x * blockDim.x + threadIdx.x;
    long s = (long)gridDim.x * blockDim.x;
    for (; i < n4; i += s) {
        float4 v = *(const float4*)&f[i * 4];
        uint2 u;
        u.x = (unsigned)f2b(v.x) | ((unsigned)f2b(v.y) << 16);
        u.y = (unsigned)f2b(v.z) | ((unsigned)f2b(v.w) << 16);
        *(uint2*)&o[i * 4] = u;
    }
}

// Wt[c][k], k in [0,256): k<128 -> W0[k][c], else W1[k-128][c]
__global__ void k_cvtW(const float* __restrict__ W0, const float* __restrict__ W1,
                       unsigned short* __restrict__ Wt) {
    int idx = blockIdx.x * blockDim.x + threadIdx.x;
    if (idx >= 128 * 256) return;
    int c = idx >> 8, k = idx & 255;
    float v = (k < 128) ? W0[k * 128 + c] : W1[(k - 128) * 128 + c];
    Wt[idx] = f2b(v);
}

// ---------------- gather: xsum[i] = sum_{j in N(i)} x[j] ----------------
// wave per NODE PAIR (CSR ranges contiguous). lane l: slot=(l>>4) in 0..3,
// col-chunk cb=(l&15)*8. Per iteration 4 independent row loads in flight/lane
// (2 per node). Reduce xor16+xor32; lanes 0-15 store node0, 16-31 node1.

template <int L>
__global__ __launch_bounds__(256) void k_gather(
    const unsigned short* __restrict__ x, const int* __restrict__ rowptr,
    const int* __restrict__ adj, unsigned short* __restrict__ xsum) {
    int wid = (blockIdx.x * blockDim.x + threadIdx.x) >> 6;
    int lane = threadIdx.x & 63;
    int nw = (gridDim.x * blockDim.x) >> 6;
    int slot = lane >> 4;
    int cb = (lane & 15) * 8;
    for (int n0 = wid * 2; n0 < NNODES; n0 += nw * 2) {
        int s0 = rowptr[n0], e0 = rowptr[n0 + 1], e1 = rowptr[n0 + 2];
        int d0 = e0 - s0, d1 = e1 - e0;
        int dmax = d0 > d1 ? d0 : d1;
        float a0[8], a1[8];
#pragma unroll
        for (int q = 0; q < 8; q++) { a0[q] = 0.f; a1[q] = 0.f; }
        for (int p = 0; p < dmax; p += 8) {
            int i00 = s0 + p + slot, i01 = i00 + 4;
            int i10 = e0 + p + slot, i11 = i10 + 4;
            uint4 v00 = make_uint4(0, 0, 0, 0), v01 = make_uint4(0, 0, 0, 0);
            uint4 v10 = make_uint4(0, 0, 0, 0), v11 = make_uint4(0, 0, 0, 0);
            if (i00 < e0) v00 = *(const uint4*)&x[(size_t)adj[i00] * 128 + cb];
            if (i01 < e0) v01 = *(const uint4*)&x[(size_t)adj[i01] * 128 + cb];
            if (i10 < e1) v10 = *(const uint4*)&x[(size_t)adj[i10] * 128 + cb];
            if (i11 < e1) v11 = *(const uint4*)&x[(size_t)adj[i11] * 128 + cb];
            unsigned w00[4] = {v00.x, v00.y, v00.z, v00.w};
            unsigned w01[4] = {v01.x, v01.y, v01.z, v01.w};
            unsigned w10[4] = {v10.x, v10.y, v10.z, v10.w};
            unsigned w11[4] = {v11.x, v11.y, v11.z, v11.w};
#pragma unroll
            for (int q = 0; q < 4; q++) {
                a0[2 * q] += b2f(w00[q] & 0xffff) + b2f(w01[q] & 0xffff);
                a0[2 * q + 1] += b2f(w00[q] >> 16) + b2f(w01[q] >> 16);
                a1[2 * q] += b2f(w10[q] & 0xffff) + b2f(w11[q] & 0xffff);
                a1[2 * q + 1] += b2f(w10[q] >> 16) + b2f(w11[q] >> 16);
            }
        }
#pragma unroll
        for (int q = 0; q < 8; q++) {
            a0[q] += __shfl_xor(a0[q], 16, 64);
            a1[q] += __shfl_xor(a1[q], 16, 64);
        }
#pragma unroll
        for (int q = 0; q < 8; q++) {
            a0[q] += __shfl_xor(a0[q], 32, 64);
            a1[q] += __shfl_xor(a1[q], 32, 64);
        }
        float sel[8];
#pragma unroll
        for (int q = 0; q < 8; q++) sel[q] = (lane < 16) ? a0[q] : a1[q];
        if (lane < 32) {
            uint4 o;
            o.x = (unsigned)f2b(sel[0]) | ((unsigned)f2b(sel[1]) << 16);
            o.y = (unsigned)f2b(sel[2]) | ((unsigned)f2b(sel[3]) << 16);
            o.z = (unsigned)f2b(sel[4]) | ((unsigned)f2b(sel[5]) << 16);
            o.w = (unsigned)f2b(sel[6]) | ((unsigned)f2b(sel[7]) << 16);
            int dst = (lane < 16) ? n0 : (n0 + 1);
            *(uint4*)&xsum[(size_t)dst * 128 + cb] = o;
        }
    }
}

// ---------------- fused GEMM: out = relu(x*W0 + xsum*W1 + b0 + deg*b1) [+feat] ----------------
// Persistent grid (1250 blocks x ~4 tiles), T14 register prefetch of the next
// tile's X/S during current tile's compute. 64-row tile, 512 thr = 8 waves
// (2M x 4N), wave tile 32x32, K=256. In-place safe: a block only reads rows
// of tiles it owns, before writing them.

#define XLD 136  // padded LDS row stride (bf16): 272 B
#define NT (NNODES / 64)

template <int RES, int L>
__global__ __launch_bounds__(512, 2) void k_gemmF(
    const unsigned short* x, const unsigned short* __restrict__ xsum,
    const unsigned short* __restrict__ Wt, const float* __restrict__ b0,
    const float* __restrict__ b1, const float* __restrict__ degf,
    const unsigned short* __restrict__ feat, unsigned short* out) {
    __shared__ __align__(16) unsigned short Xs[64 * XLD];
    __shared__ __align__(16) unsigned short Ss[64 * XLD];

    int tid = threadIdx.x;
    int wave = tid >> 6, lane = tid & 63;
    int wm = wave >> 2, wn = wave & 3;
    int kg = (lane >> 4) << 3;  // 0,8,16,24
    int cl = lane & 15;

    // per-thread constant epilogue params (hoisted out of tile loop)
    float bias0[2], bias1[2];
#pragma unroll
    for (int nf = 0; nf < 2; nf++) {
        int c = wn * 32 + nf * 16 + cl;
        bias0[nf] = b0[c];
        bias1[nf] = b1[c];
    }

    // staging coords: thread covers elems e=(it*512+tid)*8
    uint4 pa[2], ps[2];
    auto loadTile = [&](int tile) {
#pragma unroll
        for (int it = 0; it < 2; ++it) {
            int e = (it * 512 + tid) * 8;
            int r = e >> 7, k = e & 127;
            pa[it] = *(const uint4*)&x[(size_t)(tile * 64 + r) * 128 + k];
            ps[it] = *(const uint4*)&xsum[(size_t)(tile * 64 + r) * 128 + k];
        }
    };

    int tile = blockIdx.x;
    if (tile < NT) loadTile(tile);
    while (tile < NT) {
        int next = tile + gridDim.x;
        __syncthreads();  // previous tile's LDS reads complete
#pragma unroll
        for (int it = 0; it < 2; ++it) {
            int e = (it * 512 + tid) * 8;
            int r = e >> 7, k = e & 127;
            *(uint4*)&Xs[r * XLD + k] = pa[it];
            *(uint4*)&Ss[r * XLD + k] = ps[it];
        }
        __syncthreads();
        if (next < NT) loadTile(next);  // in flight across compute

        int rowBase = tile * 64;
        f32x4 acc[2][2];
#pragma unroll
        for (int i = 0; i < 2; i++)
#pragma unroll
            for (int j = 0; j < 2; j++) acc[i][j] = (f32x4){0.f, 0.f, 0.f, 0.f};

#pragma unroll
        for (int ks = 0; ks < 8; ++ks) {
            const unsigned short* src = (ks < 4) ? Xs : Ss;
            int kk = (ks & 3) * 32 + kg;
            short8 aF[2];
#pragma unroll
            for (int mf = 0; mf < 2; ++mf) {
                int r = wm * 32 + mf * 16 + cl;
                aF[mf] = *(const short8*)&src[r * XLD + kk];
            }
#pragma unroll
            for (int nf = 0; nf < 2; nf++) {
                int c = wn * 32 + nf * 16 + cl;
                short8 bF = *(const short8*)&Wt[(size_t)c * 256 + ks * 32 + kg];
#pragma unroll
                for (int mf = 0; mf < 2; mf++)
                    acc[mf][nf] = __builtin_amdgcn_mfma_f32_16x16x32_bf16(
                        aF[mf], bF, acc[mf][nf], 0, 0, 0);
            }
        }

        // epilogue: D col = lane&15, row = (lane>>4)*4+q (verified layout)
#pragma unroll
        for (int nf = 0; nf < 2; nf++) {
            int c = wn * 32 + nf * 16 + cl;
#pragma unroll
            for (int mf = 0; mf < 2; mf++) {
                int r0 = rowBase + wm * 32 + mf * 16 + ((lane >> 4) << 2);
                f32x4 d = acc[mf][nf];
#pragma unroll
                for (int q = 0; q < 4; q++) {
                    int r = r0 + q;
                    float v = d[q] + bias0[nf] + degf[r] * bias1[nf];
                    v = fmaxf(v, 0.f);
                    if (RES) v += b2f(feat[(size_t)r * 128 + c]);
                    out[(size_t)r * 128 + c] = f2b(v);
                }
            }
        }
        tile = next;
    }
}

// ---------------- final layer: d_out[i][0..2] = act_i*W0 + hsum_i*W1 + b0 + deg*b1 ----------------

__global__ __launch_bounds__(256) void k_fin(
    const unsigned short* __restrict__ act, const unsigned short* __restrict__ hsum,
    const float* __restrict__ W0, const float* __restrict__ W1,
    const float* __restrict__ b0, const float* __restrict__ b1,
    const float* __restrict__ degf, float* __restrict__ out) {
    __shared__ __align__(16) unsigned short xa[64 * XLD];
    __shared__ __align__(16) unsigned short xs2[64 * XLD];
    __shared__ float Wf[768];
    __shared__ float ps[64][4][4];

    int tid = threadIdx.x;
    int nodeBase = blockIdx.x * 64;

    for (int idx = tid; idx < 384; idx += 256) {
        Wf[idx] = W0[idx];
        Wf[384 + idx] = W1[idx];
    }
#pragma unroll
    for (int it = 0; it < 4; ++it) {
        int e = (it * 256 + tid) * 8;
        int r = e >> 7, k = e & 127;
        *(uint4*)&xa[r * XLD + k] = *(const uint4*)&act[(size_t)(nodeBase + r) * 128 + k];
        *(uint4*)&xs2[r * XLD + k] =
            *(const uint4*)&hsum[(size_t)(nodeBase + r) * 128 + k];
    }
    __syncthreads();

    int n = tid >> 2, q = tid & 3;
    const unsigned short* src = (q < 2) ? xa : xs2;
    int kloc = (q & 1) * 64;
    float a0 = 0.f, a1 = 0.f, a2 = 0.f;
#pragma unroll
    for (int kk = 0; kk < 64; kk += 8) {
        uint4 v = *(const uint4*)&src[n * XLD + kloc + kk];
        unsigned vv[4] = {v.x, v.y, v.z, v.w};
#pragma unroll
        for (int t = 0; t < 4; t++) {
            int kgl = q * 64 + kk + 2 * t;
            float x0 = b2f(vv[t] & 0xffff), x1 = b2f(vv[t] >> 16);
            const float* w = &Wf[kgl * 3];
            a0 += x0 * w[0] + x1 * w[3];
            a1 += x0 * w[1] + x1 * w[4];
            a2 += x0 * w[2] + x1 * w[5];
        }
    }
    ps[n][q][0] = a0;
    ps[n][q][1] = a1;
    ps[n][q][2] = a2;
    __syncthreads();
    if (q == 0) {
        int node = nodeBase + n;
        float dg = degf[node];
#pragma unroll
        for (int c = 0; c < 3; c++) {
            float d = ps[n][0][c] + ps[n][1][c] + ps[n][2][c] + ps[n][3][c] +
                      b0[c] + dg * b1[c];
            out[(size_t)node * 3 + c] = d;
        }
    }
}

// ---------------- launch ----------------

extern "C" void kernel_launch(void* const* d_in, const int* in_sizes, int n_in,
                              void* d_out, int out_size, void* d_ws, size_t ws_size,
                              hipStream_t stream) {
    const float* features = (const float*)d_in[0];
    const int* edges = (const int*)d_in[1];
    const float *W0[4], *B0[4], *W1[4], *B1[4];
    for (int i = 0; i < 4; i++) {
        W0[i] = (const float*)d_in[2 + 4 * i];
        B0[i] = (const float*)d_in[3 + 4 * i];
        W1[i] = (const float*)d_in[4 + 4 * i];
        B1[i] = (const float*)d_in[5 + 4 * i];
    }

    char* p = (char*)d_ws;
    auto alloc = [&](size_t bytes) {
        void* r = (void*)p;
        p += (bytes + 255) & ~(size_t)255;
        return r;
    };
    int* rowptr = (int*)alloc((NNODES + 1) * sizeof(int));
    int* cursor = (int*)alloc((NNODES + 1) * sizeof(int));
    float* degf = (float*)alloc(NNODES * sizeof(float));
    int* adj = (int*)alloc((size_t)2 * NEDGES * sizeof(int));
    int* bsum = (int*)alloc(1024);
    unsigned short* feat_bf = (unsigned short*)alloc((size_t)NNODES * 128 * 2);
    unsigned short* act = (unsigned short*)alloc((size_t)NNODES * 128 * 2);
    unsigned short* xsum = (unsigned short*)alloc((size_t)NNODES * 128 * 2);
    unsigned short* Wtb = (unsigned short*)alloc((size_t)3 * 128 * 256 * 2);

    // CSR build (XCD-partitioned count/fill)
    k_zero<<<1024, 256, 0, stream>>>(cursor, NNODES + 1);
    k_count<<<2048, 256, 0, stream>>>(edges, cursor);
    k_scan1<<<SCAN_NB, SCAN_BLOCK, 0, stream>>>(cursor, bsum);
    k_scan2<<<1, 256, 0, stream>>>(bsum, rowptr);
    k_scan3<<<SCAN_NB, SCAN_BLOCK, 0, stream>>>(cursor, rowptr, bsum, degf);
    k_fill<<<2048, 256, 0, stream>>>(edges, cursor, adj);

    // conversions
    k_cvt<<<2048, 256, 0, stream>>>(features, feat_bf, (long)NNODES * 128 / 4);
    for (int l = 0; l < 3; l++)
        k_cvtW<<<128, 256, 0, stream>>>(W0[l], W1[l], Wtb + (size_t)l * 128 * 256);

    // layer 0
    k_gather<0><<<8192, 256, 0, stream>>>(feat_bf, rowptr, adj, xsum);
    k_gemmF<0, 0><<<1250, 512, 0, stream>>>(feat_bf, xsum, Wtb, B0[0], B1[0], degf,
                                            nullptr, act);
    // layer 1 (in-place act -> act; blocks only read rows they own, pre-write)
    k_gather<1><<<8192, 256, 0, stream>>>(act, rowptr, adj, xsum);
    k_gemmF<0, 1><<<1250, 512, 0, stream>>>(act, xsum, Wtb + 128 * 256, B0[1], B1[1],
                                            degf, nullptr, act);
    // layer 2 (+residual)
    k_gather<2><<<8192, 256, 0, stream>>>(act, rowptr, adj, xsum);
    k_gemmF<1, 2><<<1250, 512, 0, stream>>>(act, xsum, Wtb + 2 * 128 * 256, B0[2],
                                            B1[2], degf, feat_bf, act);
    // final layer
    k_gather<3><<<8192, 256, 0, stream>>>(act, rowptr, adj, xsum);
    k_fin<<<NNODES / 64, 256, 0, stream>>>(act, xsum, W0[3], W1[3], B0[3], B1[3],
                                           degf, (float*)d_out);
}

// Round 7
// 1089.405 us; speedup vs baseline: 1.2237x; 1.0731x over previous
//
#include <hip/hip_runtime.h>
#include <hip/hip_bf16.h>

#define NNODES 320000
#define NEDGES 960000
#define NPART 8
#define PARTSZ (NNODES / NPART)  // 40000

typedef __attribute__((ext_vector_type(8))) short short8;
typedef __attribute__((ext_vector_type(4))) float f32x4;

__device__ __forceinline__ float b2f(unsigned short u) {
    return __uint_as_float(((unsigned)u) << 16);
}
__device__ __forceinline__ unsigned short f2b(float f) {
    __hip_bfloat16 h = __float2bfloat16(f);
    union { __hip_bfloat16 h; unsigned short u; } cv;
    cv.h = h;
    return cv.u;
}

// ---------------- CSR build (XCD-partitioned: blockIdx&7 == node-range owner) ----------------

__global__ void k_zero(int* p, int n) {
    int i = blockIdx.x * blockDim.x + threadIdx.x;
    int s = gridDim.x * blockDim.x;
    for (; i < n; i += s) p[i] = 0;
}

__global__ void k_count(const int* __restrict__ edges, int* __restrict__ deg) {
    int r = blockIdx.x & (NPART - 1);
    int lo = r * PARTSZ, hi = lo + PARTSZ;
    int i = (blockIdx.x >> 3) * blockDim.x + threadIdx.x;
    int s = (gridDim.x >> 3) * blockDim.x;
    for (; i < NEDGES; i += s) {
        int2 e = *(const int2*)&edges[2 * i];
        if (e.x >= lo && e.x < hi) atomicAdd(&deg[e.x], 1);
        if (e.y >= lo && e.y < hi) atomicAdd(&deg[e.y], 1);
    }
}

#define SCAN_BLOCK 256
#define SCAN_ITEMS 8
#define SCAN_CHUNK 2048
#define SCAN_NB 157  // ceil(320000/2048)

__global__ void k_scan1(const int* __restrict__ deg, int* __restrict__ bsum) {
    __shared__ int sd[SCAN_BLOCK];
    int b = blockIdx.x, t = threadIdx.x;
    int base = b * SCAN_CHUNK + t * SCAN_ITEMS;
    int s = 0;
    for (int i = 0; i < SCAN_ITEMS; i++) {
        int g = base + i;
        if (g < NNODES) s += deg[g];
    }
    sd[t] = s;
    __syncthreads();
    for (int off = 128; off > 0; off >>= 1) {
        if (t < off) sd[t] += sd[t + off];
        __syncthreads();
    }
    if (t == 0) bsum[b] = sd[0];
}

// parallel exclusive scan of the 157 block sums
__global__ void k_scan2(int* bsum, int* rowptr) {
    __shared__ int sd[256];
    int t = threadIdx.x;
    int v = (t < SCAN_NB) ? bsum[t] : 0;
    sd[t] = v;
    __syncthreads();
    for (int off = 1; off < 256; off <<= 1) {
        int x = (t >= off) ? sd[t - off] : 0;
        __syncthreads();
        sd[t] += x;
        __syncthreads();
    }
    if (t < SCAN_NB) bsum[t] = sd[t] - v;  // exclusive prefix
    if (t == SCAN_NB - 1) rowptr[NNODES] = sd[t];
}

__global__ void k_scan3(int* __restrict__ deg_cursor, int* __restrict__ rowptr,
                        const int* __restrict__ bsum, float* __restrict__ degf) {
    __shared__ int sd[SCAN_BLOCK];
    int b = blockIdx.x, t = threadIdx.x;
    int base = b * SCAN_CHUNK + t * SCAN_ITEMS;
    int v[SCAN_ITEMS];
    int s = 0;
    for (int i = 0; i < SCAN_ITEMS; i++) {
        int g = base + i;
        v[i] = (g < NNODES) ? deg_cursor[g] : 0;
        s += v[i];
    }
    sd[t] = s;
    __syncthreads();
    for (int off = 1; off < SCAN_BLOCK; off <<= 1) {
        int x = (t >= off) ? sd[t - off] : 0;
        __syncthreads();
        sd[t] += x;
        __syncthreads();
    }
    int prefix = bsum[b] + (sd[t] - s);  // exclusive over threads
    for (int i = 0; i < SCAN_ITEMS; i++) {
        int g = base + i;
        if (g < NNODES) {
            rowptr[g] = prefix;
            deg_cursor[g] = prefix;  // cursor init
            degf[g] = (float)v[i];
            prefix += v[i];
        }
    }
}

__global__ void k_fill(const int* __restrict__ edges, int* __restrict__ cursor,
                       int* __restrict__ adj) {
    int r = blockIdx.x & (NPART - 1);
    int lo = r * PARTSZ, hi = lo + PARTSZ;
    int i = (blockIdx.x >> 3) * blockDim.x + threadIdx.x;
    int s = (gridDim.x >> 3) * blockDim.x;
    for (; i < NEDGES; i += s) {
        int2 e = *(const int2*)&edges[2 * i];
        if (e.x >= lo && e.x < hi) adj[atomicAdd(&cursor[e.x], 1)] = e.y;
        if (e.y >= lo && e.y < hi) adj[atomicAdd(&cursor[e.y], 1)] = e.x;
    }
}

// ---------------- conversions ----------------

__global__ void k_cvt(const float* __restrict__ f, unsigned short* __restrict__ o,
                      long n4) {
    long i = (long)blockIdx.x * blockDim.x + threadIdx.x;
    long s = (long)gridDim.x * blockDim.x;
    for (; i < n4; i += s) {
        float4 v = *(const float4*)&f[i * 4];
        uint2 u;
        u.x = (unsigned)f2b(v.x) | ((unsigned)f2b(v.y) << 16);
        u.y = (unsigned)f2b(v.z) | ((unsigned)f2b(v.w) << 16);
        *(uint2*)&o[i * 4] = u;
    }
}

// Wt[c][k], k in [0,256): k<128 -> W0[k][c], else W1[k-128][c]
__global__ void k_cvtW(const float* __restrict__ W0, const float* __restrict__ W1,
                       unsigned short* __restrict__ Wt) {
    int idx = blockIdx.x * blockDim.x + threadIdx.x;
    if (idx >= 128 * 256) return;
    int c = idx >> 8, k = idx & 255;
    float v = (k < 128) ? W0[k * 128 + c] : W1[(k - 128) * 128 + c];
    Wt[idx] = f2b(v);
}

// ---------------- gather: xsum[i] = sum_{j in N(i)} x[j] ----------------
// wave per NODE PAIR (CSR ranges contiguous). lane l: slot=(l>>4) in 0..3,
// col-chunk cb=(l&15)*8. 4 independent row loads in flight/lane.

template <int L>
__global__ __launch_bounds__(256) void k_gather(
    const unsigned short* __restrict__ x, const int* __restrict__ rowptr,
    const int* __restrict__ adj, unsigned short* __restrict__ xsum) {
    int wid = (blockIdx.x * blockDim.x + threadIdx.x) >> 6;
    int lane = threadIdx.x & 63;
    int nw = (gridDim.x * blockDim.x) >> 6;
    int slot = lane >> 4;
    int cb = (lane & 15) * 8;
    for (int n0 = wid * 2; n0 < NNODES; n0 += nw * 2) {
        int s0 = rowptr[n0], e0 = rowptr[n0 + 1], e1 = rowptr[n0 + 2];
        int d0 = e0 - s0, d1 = e1 - e0;
        int dmax = d0 > d1 ? d0 : d1;
        float a0[8], a1[8];
#pragma unroll
        for (int q = 0; q < 8; q++) { a0[q] = 0.f; a1[q] = 0.f; }
        for (int p = 0; p < dmax; p += 8) {
            int i00 = s0 + p + slot, i01 = i00 + 4;
            int i10 = e0 + p + slot, i11 = i10 + 4;
            uint4 v00 = make_uint4(0, 0, 0, 0), v01 = make_uint4(0, 0, 0, 0);
            uint4 v10 = make_uint4(0, 0, 0, 0), v11 = make_uint4(0, 0, 0, 0);
            if (i00 < e0) v00 = *(const uint4*)&x[(size_t)adj[i00] * 128 + cb];
            if (i01 < e0) v01 = *(const uint4*)&x[(size_t)adj[i01] * 128 + cb];
            if (i10 < e1) v10 = *(const uint4*)&x[(size_t)adj[i10] * 128 + cb];
            if (i11 < e1) v11 = *(const uint4*)&x[(size_t)adj[i11] * 128 + cb];
            unsigned w00[4] = {v00.x, v00.y, v00.z, v00.w};
            unsigned w01[4] = {v01.x, v01.y, v01.z, v01.w};
            unsigned w10[4] = {v10.x, v10.y, v10.z, v10.w};
            unsigned w11[4] = {v11.x, v11.y, v11.z, v11.w};
#pragma unroll
            for (int q = 0; q < 4; q++) {
                a0[2 * q] += b2f(w00[q] & 0xffff) + b2f(w01[q] & 0xffff);
                a0[2 * q + 1] += b2f(w00[q] >> 16) + b2f(w01[q] >> 16);
                a1[2 * q] += b2f(w10[q] & 0xffff) + b2f(w11[q] & 0xffff);
                a1[2 * q + 1] += b2f(w10[q] >> 16) + b2f(w11[q] >> 16);
            }
        }
#pragma unroll
        for (int q = 0; q < 8; q++) {
            a0[q] += __shfl_xor(a0[q], 16, 64);
            a1[q] += __shfl_xor(a1[q], 16, 64);
        }
#pragma unroll
        for (int q = 0; q < 8; q++) {
            a0[q] += __shfl_xor(a0[q], 32, 64);
            a1[q] += __shfl_xor(a1[q], 32, 64);
        }
        float sel[8];
#pragma unroll
        for (int q = 0; q < 8; q++) sel[q] = (lane < 16) ? a0[q] : a1[q];
        if (lane < 32) {
            uint4 o;
            o.x = (unsigned)f2b(sel[0]) | ((unsigned)f2b(sel[1]) << 16);
            o.y = (unsigned)f2b(sel[2]) | ((unsigned)f2b(sel[3]) << 16);
            o.z = (unsigned)f2b(sel[4]) | ((unsigned)f2b(sel[5]) << 16);
            o.w = (unsigned)f2b(sel[6]) | ((unsigned)f2b(sel[7]) << 16);
            int dst = (lane < 16) ? n0 : (n0 + 1);
            *(uint4*)&xsum[(size_t)dst * 128 + cb] = o;
        }
    }
}

// ---------------- fused GEMM: out = relu(x*W0 + xsum*W1 + b0 + deg*b1) [+feat] ----------------
// Persistent grid (1250 blocks x 4 tiles), register prefetch of the next
// tile's X/S during current tile's compute. 64-row tile, 512 thr = 8 waves
// (2M x 4N), wave tile 32x32, K=256. launch_bounds(512,4) -> 2 blocks/CU.

#define XLD 136  // padded LDS row stride (bf16): 272 B
#define NT (NNODES / 64)

template <int RES, int L>
__global__ __launch_bounds__(512, 4) void k_gemmF(
    const unsigned short* x, const unsigned short* __restrict__ xsum,
    const unsigned short* __restrict__ Wt, const float* __restrict__ b0,
    const float* __restrict__ b1, const float* __restrict__ degf,
    const unsigned short* __restrict__ feat, unsigned short* out) {
    __shared__ __align__(16) unsigned short Xs[64 * XLD];
    __shared__ __align__(16) unsigned short Ss[64 * XLD];

    int tid = threadIdx.x;
    int wave = tid >> 6, lane = tid & 63;
    int wm = wave >> 2, wn = wave & 3;
    int kg = (lane >> 4) << 3;  // 0,8,16,24
    int cl = lane & 15;

    float bias0[2], bias1[2];
#pragma unroll
    for (int nf = 0; nf < 2; nf++) {
        int c = wn * 32 + nf * 16 + cl;
        bias0[nf] = b0[c];
        bias1[nf] = b1[c];
    }

    uint4 pa[2], ps[2];
    auto loadTile = [&](int tile) {
#pragma unroll
        for (int it = 0; it < 2; ++it) {
            int e = (it * 512 + tid) * 8;
            int r = e >> 7, k = e & 127;
            pa[it] = *(const uint4*)&x[(size_t)(tile * 64 + r) * 128 + k];
            ps[it] = *(const uint4*)&xsum[(size_t)(tile * 64 + r) * 128 + k];
        }
    };

    int tile = blockIdx.x;
    if (tile < NT) loadTile(tile);
    while (tile < NT) {
        int next = tile + gridDim.x;
        __syncthreads();  // previous tile's LDS reads complete
#pragma unroll
        for (int it = 0; it < 2; ++it) {
            int e = (it * 512 + tid) * 8;
            int r = e >> 7, k = e & 127;
            *(uint4*)&Xs[r * XLD + k] = pa[it];
            *(uint4*)&Ss[r * XLD + k] = ps[it];
        }
        __syncthreads();
        if (next < NT) loadTile(next);  // in flight across compute

        int rowBase = tile * 64;
        f32x4 acc[2][2];
#pragma unroll
        for (int i = 0; i < 2; i++)
#pragma unroll
            for (int j = 0; j < 2; j++) acc[i][j] = (f32x4){0.f, 0.f, 0.f, 0.f};

#pragma unroll
        for (int ks = 0; ks < 8; ++ks) {
            const unsigned short* src = (ks < 4) ? Xs : Ss;
            int kk = (ks & 3) * 32 + kg;
            short8 aF[2];
#pragma unroll
            for (int mf = 0; mf < 2; ++mf) {
                int r = wm * 32 + mf * 16 + cl;
                aF[mf] = *(const short8*)&src[r * XLD + kk];
            }
#pragma unroll
            for (int nf = 0; nf < 2; nf++) {
                int c = wn * 32 + nf * 16 + cl;
                short8 bF = *(const short8*)&Wt[(size_t)c * 256 + ks * 32 + kg];
#pragma unroll
                for (int mf = 0; mf < 2; mf++)
                    acc[mf][nf] = __builtin_amdgcn_mfma_f32_16x16x32_bf16(
                        aF[mf], bF, acc[mf][nf], 0, 0, 0);
            }
        }

        // epilogue: D col = lane&15, row = (lane>>4)*4+q (verified layout)
#pragma unroll
        for (int nf = 0; nf < 2; nf++) {
            int c = wn * 32 + nf * 16 + cl;
#pragma unroll
            for (int mf = 0; mf < 2; mf++) {
                int r0 = rowBase + wm * 32 + mf * 16 + ((lane >> 4) << 2);
                f32x4 d = acc[mf][nf];
#pragma unroll
                for (int q = 0; q < 4; q++) {
                    int r = r0 + q;
                    float v = d[q] + bias0[nf] + degf[r] * bias1[nf];
                    v = fmaxf(v, 0.f);
                    if (RES) v += b2f(feat[(size_t)r * 128 + c]);
                    out[(size_t)r * 128 + c] = f2b(v);
                }
            }
        }
        tile = next;
    }
}

// ---------------- final layer, step 1: h3[i] = {act_i*W0_3, act_i*W1_3} (no bias) ----------------
// 128 nodes/block, 2 thr/node (half 0: W0 dot, half 1: W1 dot). h3[N][8] f32.

#define LDK3 136

__global__ __launch_bounds__(256) void k_fin3(
    const unsigned short* __restrict__ act, const float* __restrict__ W0p,
    const float* __restrict__ W1p, float* __restrict__ h3) {
    __shared__ __align__(16) unsigned short xs[128 * LDK3];
    __shared__ float Ws[128 * 8];
    int tid = threadIdx.x;
    int nodeBase = blockIdx.x * 128;

    for (int idx = tid; idx < 384; idx += 256) {
        int k = idx / 3, c = idx - k * 3;
        Ws[k * 8 + c] = W0p[idx];
        Ws[k * 8 + 4 + c] = W1p[idx];
    }
    for (int it = 0; it < 8; ++it) {
        int e = (it * 256 + tid) * 8;
        int r = e >> 7;
        int k = e & 127;
        *(uint4*)&xs[r * LDK3 + k] = *(const uint4*)&act[(size_t)(nodeBase + r) * 128 + k];
    }
    __syncthreads();

    int n = tid >> 1, half = tid & 1;
    float a0 = 0.f, a1 = 0.f, a2 = 0.f;
#pragma unroll
    for (int k0 = 0; k0 < 128; k0 += 8) {
        uint4 v = *(const uint4*)&xs[n * LDK3 + k0];
        unsigned vv[4] = {v.x, v.y, v.z, v.w};
#pragma unroll
        for (int q = 0; q < 4; q++) {
            int k = k0 + 2 * q;
            float x0 = b2f(vv[q] & 0xffff), x1 = b2f(vv[q] >> 16);
            const float* w = &Ws[k * 8 + half * 4];
            a0 += x0 * w[0] + x1 * w[8];
            a1 += x0 * w[1] + x1 * w[9];
            a2 += x0 * w[2] + x1 * w[10];
        }
    }
    float* dst = &h3[(size_t)(nodeBase + n) * 8 + half * 4];
    dst[0] = a0;
    dst[1] = a1;
    dst[2] = a2;
}

// ---------------- final layer, step 2: out[i] = d_i + b0 + deg*b1 + sum_nbr z_j ----------------
// z-table is 16B rows, 10 MB -> L2/L3 resident; unroll-2 neighbor loop.

__global__ void k_agg3(const float* __restrict__ h3, const int* __restrict__ rowptr,
                       const int* __restrict__ adj, const float* __restrict__ b0,
                       const float* __restrict__ b1, const float* __restrict__ degf,
                       float* __restrict__ out) {
    int i = blockIdx.x * blockDim.x + threadIdx.x;
    int stride = gridDim.x * blockDim.x;
    for (int node = i; node < NNODES; node += stride) {
        float4 dv = *(const float4*)&h3[(size_t)node * 8];
        float dg = degf[node];
        float a0 = dv.x + b0[0] + dg * b1[0];
        float a1 = dv.y + b0[1] + dg * b1[1];
        float a2 = dv.z + b0[2] + dg * b1[2];
        int s = rowptr[node], e = rowptr[node + 1];
        int p = s;
        for (; p + 2 <= e; p += 2) {
            int j0 = adj[p], j1 = adj[p + 1];
            float4 v0 = *(const float4*)&h3[(size_t)j0 * 8 + 4];
            float4 v1 = *(const float4*)&h3[(size_t)j1 * 8 + 4];
            a0 += v0.x + v1.x;
            a1 += v0.y + v1.y;
            a2 += v0.z + v1.z;
        }
        if (p < e) {
            float4 v = *(const float4*)&h3[(size_t)adj[p] * 8 + 4];
            a0 += v.x;
            a1 += v.y;
            a2 += v.z;
        }
        out[(size_t)node * 3 + 0] = a0;
        out[(size_t)node * 3 + 1] = a1;
        out[(size_t)node * 3 + 2] = a2;
    }
}

// ---------------- launch ----------------

extern "C" void kernel_launch(void* const* d_in, const int* in_sizes, int n_in,
                              void* d_out, int out_size, void* d_ws, size_t ws_size,
                              hipStream_t stream) {
    const float* features = (const float*)d_in[0];
    const int* edges = (const int*)d_in[1];
    const float *W0[4], *B0[4], *W1[4], *B1[4];
    for (int i = 0; i < 4; i++) {
        W0[i] = (const float*)d_in[2 + 4 * i];
        B0[i] = (const float*)d_in[3 + 4 * i];
        W1[i] = (const float*)d_in[4 + 4 * i];
        B1[i] = (const float*)d_in[5 + 4 * i];
    }

    char* p = (char*)d_ws;
    auto alloc = [&](size_t bytes) {
        void* r = (void*)p;
        p += (bytes + 255) & ~(size_t)255;
        return r;
    };
    int* rowptr = (int*)alloc((NNODES + 1) * sizeof(int));
    int* cursor = (int*)alloc((NNODES + 1) * sizeof(int));
    float* degf = (float*)alloc(NNODES * sizeof(float));
    int* adj = (int*)alloc((size_t)2 * NEDGES * sizeof(int));
    int* bsum = (int*)alloc(1024);
    unsigned short* feat_bf = (unsigned short*)alloc((size_t)NNODES * 128 * 2);
    unsigned short* act = (unsigned short*)alloc((size_t)NNODES * 128 * 2);
    unsigned short* xsum = (unsigned short*)alloc((size_t)NNODES * 128 * 2);
    unsigned short* Wtb = (unsigned short*)alloc((size_t)3 * 128 * 256 * 2);
    float* h3 = (float*)xsum;  // alias: xsum free during final layer

    // CSR build (XCD-partitioned count/fill)
    k_zero<<<1024, 256, 0, stream>>>(cursor, NNODES + 1);
    k_count<<<2048, 256, 0, stream>>>(edges, cursor);
    k_scan1<<<SCAN_NB, SCAN_BLOCK, 0, stream>>>(cursor, bsum);
    k_scan2<<<1, 256, 0, stream>>>(bsum, rowptr);
    k_scan3<<<SCAN_NB, SCAN_BLOCK, 0, stream>>>(cursor, rowptr, bsum, degf);
    k_fill<<<2048, 256, 0, stream>>>(edges, cursor, adj);

    // conversions
    k_cvt<<<2048, 256, 0, stream>>>(features, feat_bf, (long)NNODES * 128 / 4);
    for (int l = 0; l < 3; l++)
        k_cvtW<<<128, 256, 0, stream>>>(W0[l], W1[l], Wtb + (size_t)l * 128 * 256);

    // layer 0
    k_gather<0><<<8192, 256, 0, stream>>>(feat_bf, rowptr, adj, xsum);
    k_gemmF<0, 0><<<1250, 512, 0, stream>>>(feat_bf, xsum, Wtb, B0[0], B1[0], degf,
                                            nullptr, act);
    // layer 1 (in-place act -> act; blocks only read rows they own, pre-write)
    k_gather<1><<<8192, 256, 0, stream>>>(act, rowptr, adj, xsum);
    k_gemmF<0, 1><<<1250, 512, 0, stream>>>(act, xsum, Wtb + 128 * 256, B0[1], B1[1],
                                            degf, nullptr, act);
    // layer 2 (+residual)
    k_gather<2><<<8192, 256, 0, stream>>>(act, rowptr, adj, xsum);
    k_gemmF<1, 2><<<1250, 512, 0, stream>>>(act, xsum, Wtb + 2 * 128 * 256, B0[2],
                                            B1[2], degf, feat_bf, act);
    // final layer: per-node 3-vecs first, then 16B-row gather
    k_fin3<<<NNODES / 128, 256, 0, stream>>>(act, W0[3], W1[3], h3);
    k_agg3<<<2048, 256, 0, stream>>>(h3, rowptr, adj, B0[3], B1[3], degf,
                                     (float*)d_out);
}